// Round 24
// baseline (136.258 us; speedup 1.0000x reference)
//
#include <hip/hip_runtime.h>
#include <hip/hip_bf16.h>

#define B_ 4
#define S_ 2048
#define D_ 768
#define H_ 12
#define HD_ 64
#define M_ (B_*S_)   // 8192
#define LOG2E 1.44269504088896f

typedef __attribute__((ext_vector_type(8))) short bf8;
typedef __attribute__((ext_vector_type(4))) float f4;
typedef unsigned short u16;
typedef unsigned int   u32;

typedef __attribute__((address_space(3))) u32 lds_u32;
typedef __attribute__((address_space(1))) const u32 glob_u32;

__device__ __forceinline__ float bf2f(u16 u) {
  union { u32 i; float f; } c; c.i = ((u32)u) << 16; return c.f;
}
__device__ __forceinline__ u16 f2bf(float x) {
  union { float f; u32 i; } c; c.f = x;
  u32 r = (c.i + 0x7FFFu + ((c.i >> 16) & 1u)) >> 16;
  return (u16)r;
}
__device__ __forceinline__ u16 cvt_bf16(float x) {
  u32 r;
  asm("v_cvt_pk_bf16_f32 %0, %1, %1" : "=v"(r) : "v"(x));
  return (u16)r;
}
__device__ __forceinline__ u32 cvt_pk2(float lo, float hi) {
  u32 r;
  asm("v_cvt_pk_bf16_f32 %0, %1, %2" : "=v"(r) : "v"(lo), "v"(hi));
  return r;
}
__device__ __forceinline__ float exp2_raw(float x) {
  float r;
  asm("v_exp_f32 %0, %1" : "=v"(r) : "v"(x));
  return r;
}
__device__ __forceinline__ void glds16(const u16* g, u16* l) {
  __builtin_amdgcn_global_load_lds((glob_u32*)g, (lds_u32*)l, 16, 0, 0);
}
// pack 8 f32 (two float4) -> bf8
__device__ __forceinline__ bf8 pack8(float4 a, float4 b) {
  union { u32 u[4]; bf8 v; } r;
  r.u[0] = cvt_pk2(a.x, a.y);
  r.u[1] = cvt_pk2(a.z, a.w);
  r.u[2] = cvt_pk2(b.x, b.y);
  r.u[3] = cvt_pk2(b.z, b.w);
  return r.v;
}

// Stage 4 weights f32 -> bf16 (blockIdx.y selects tensor).
__global__ __launch_bounds__(256) void stage_w4(const float* __restrict__ w0, const float* __restrict__ w1,
                                                const float* __restrict__ w2, const float* __restrict__ w3,
                                                u16* __restrict__ o0, u16* __restrict__ o1,
                                                u16* __restrict__ o2, u16* __restrict__ o3, int n4)
{
  int y = blockIdx.y;
  const float* src = (y == 0) ? w0 : (y == 1) ? w1 : (y == 2) ? w2 : w3;
  u16*         dst = (y == 0) ? o0 : (y == 1) ? o1 : (y == 2) ? o2 : o3;
  for (int i = blockIdx.x * blockDim.x + threadIdx.x; i < n4; i += gridDim.x * blockDim.x) {
    float4 v = ((const float4*)src)[i];
    ushort4 o;
    o.x = f2bf(v.x); o.y = f2bf(v.y); o.z = f2bf(v.z); o.w = f2bf(v.w);
    ((ushort4*)dst)[i] = o;
  }
}

// f32 -> bf16 (fallback x staging)
__global__ __launch_bounds__(256) void stage_cvt(const float* __restrict__ in,
                                                 u16* __restrict__ out, int n4)
{
  for (int i = blockIdx.x * blockDim.x + threadIdx.x; i < n4; i += gridDim.x * blockDim.x) {
    float4 v = ((const float4*)in)[i];
    ushort4 o;
    o.x = f2bf(v.x); o.y = f2bf(v.y); o.z = f2bf(v.z); o.w = f2bf(v.w);
    ((ushort4*)out)[i] = o;
  }
}

__device__ __forceinline__ bf8 ldcvt8(const float* __restrict__ p) {
  float4 a = *(const float4*)p;
  float4 b = *(const float4*)(p + 4);
  bf8 r;
  r[0] = f2bf(a.x); r[1] = f2bf(a.y); r[2] = f2bf(a.z); r[3] = f2bf(a.w);
  r[4] = f2bf(b.x); r[5] = f2bf(b.y); r[6] = f2bf(b.z); r[7] = f2bf(b.w);
  return r;
}

#define MFMA_BF16 __builtin_amdgcn_mfma_f32_16x16x32_bf16

// GEMM v5b core: tile 64x128, BK=64. B staged via glds16 (linear + XOR chunk
// swizzle). A: AF32=0 -> glds16 from bf16 A16; AF32=1 -> reg-staged from f32
// A32 (same LDS layout: slot s at row holds chunk s^(row&7)). SAFE ordering:
// B drained with vmcnt(0) BEFORE barrier; A-prefetch issued AFTER barrier so
// it flies across compute and is drained by the next __syncthreads().
// EPI: 0 bf16; 1 norm; 2 norm*temp*log2e; 3 f32; 4 V-transposed store.
template <int EPI, int AF32>
__device__ __forceinline__ void gemm_core(u16* lds, int row0, int col0,
                                          const u16* __restrict__ A16,
                                          const float* __restrict__ A32,
                                          const u16* __restrict__ W,
                                          u16* __restrict__ Cb,
                                          float* __restrict__ Cf,
                                          const float* __restrict__ temp)
{
  u16* a_lds = lds;
  u16* b_lds = lds + 64 * 64;

  const int w  = threadIdx.x >> 6;
  const int ln = threadIdx.x & 63;
  const int li = ln & 15, g = ln >> 4;
  const int wr = w >> 1, wc = w & 1;

  const int srow = ln >> 3;
  const int scol = ((ln & 7) ^ srow) * 8;
  const u16* Bbase = W + (size_t)(col0 + srow) * 768 + scol;
  const u16* Abase16 = AF32 ? nullptr : A16 + (size_t)(row0 + srow) * 768 + scol;

  // AF32 reg-staging: thread covers row rA = tid>>2, slots s0, s0+1
  const int rA = threadIdx.x >> 2;
  const int s0 = (threadIdx.x & 3) * 2;
  const int c0g = (s0 ^ (rA & 7)) * 8;
  const int c1g = ((s0 + 1) ^ (rA & 7)) * 8;
  const float* Arow = AF32 ? A32 + (size_t)(row0 + rA) * 768 : nullptr;

  float4 ar0a, ar0b, ar1a, ar1b;
  if (AF32) {
    ar0a = *(const float4*)(Arow + c0g);
    ar0b = *(const float4*)(Arow + c0g + 4);
    ar1a = *(const float4*)(Arow + c1g);
    ar1b = *(const float4*)(Arow + c1g + 4);
  }

  f4 acc[2][4];
#pragma unroll
  for (int i = 0; i < 2; ++i)
#pragma unroll
    for (int j = 0; j < 4; ++j) acc[i][j] = (f4){0.f, 0.f, 0.f, 0.f};

  for (int kt = 0; kt < 12; ++kt) {
    const int k0 = kt * 64;
    __syncthreads();   // full drain: prior compute + any in-flight prefetch
    if (AF32) {
      // compiler inserts reg-dependency waits for ar* here -> all older vmem retired
      *(bf8*)(a_lds + rA * 64 + s0 * 8)       = pack8(ar0a, ar0b);
      *(bf8*)(a_lds + rA * 64 + (s0 + 1) * 8) = pack8(ar1a, ar1b);
    } else {
#pragma unroll
      for (int i = 0; i < 2; ++i) {
        int seg = w * 2 + i;
        glds16(Abase16 + (size_t)(seg * 8) * 768 + k0, a_lds + seg * 512);
      }
    }
#pragma unroll
    for (int i = 0; i < 4; ++i) {
      int seg = w * 4 + i;
      glds16(Bbase + (size_t)(seg * 8) * 768 + k0, b_lds + seg * 512);
    }
    // only B DMA outstanding here -> vmcnt(0) == "B done"
    asm volatile("s_waitcnt vmcnt(0)" ::: "memory");
    asm volatile("s_waitcnt lgkmcnt(0)" ::: "memory");
    __builtin_amdgcn_s_barrier();
    if (AF32 && kt < 11) {
      // prefetch next A tile; flies across compute, drained at next __syncthreads
      const float* an = Arow + (kt + 1) * 64;
      ar0a = *(const float4*)(an + c0g);
      ar0b = *(const float4*)(an + c0g + 4);
      ar1a = *(const float4*)(an + c1g);
      ar1b = *(const float4*)(an + c1g + 4);
    }

#pragma unroll
    for (int kk = 0; kk < 2; ++kk) {
      const int co = (((kk * 4 + g) ^ (li & 7)) * 8);
      bf8 a0 = *(const bf8*)(a_lds + (wr * 32 + li) * 64 + co);
      bf8 a1 = *(const bf8*)(a_lds + (wr * 32 + 16 + li) * 64 + co);
      bf8 b0 = *(const bf8*)(b_lds + (wc * 64 + li) * 64 + co);
      bf8 b1 = *(const bf8*)(b_lds + (wc * 64 + 16 + li) * 64 + co);
      bf8 b2 = *(const bf8*)(b_lds + (wc * 64 + 32 + li) * 64 + co);
      bf8 b3 = *(const bf8*)(b_lds + (wc * 64 + 48 + li) * 64 + co);
      acc[0][0] = MFMA_BF16(a0, b0, acc[0][0], 0, 0, 0);
      acc[0][1] = MFMA_BF16(a0, b1, acc[0][1], 0, 0, 0);
      acc[0][2] = MFMA_BF16(a0, b2, acc[0][2], 0, 0, 0);
      acc[0][3] = MFMA_BF16(a0, b3, acc[0][3], 0, 0, 0);
      acc[1][0] = MFMA_BF16(a1, b0, acc[1][0], 0, 0, 0);
      acc[1][1] = MFMA_BF16(a1, b1, acc[1][1], 0, 0, 0);
      acc[1][2] = MFMA_BF16(a1, b2, acc[1][2], 0, 0, 0);
      acc[1][3] = MFMA_BF16(a1, b3, acc[1][3], 0, 0, 0);
    }
  }

  const int wrow0 = row0 + wr * 32;
  const int wcol0 = col0 + wc * 64;

  if (EPI == 1 || EPI == 2) {
    float tmul = 1.0f;
    if (EPI == 2) tmul = temp[wcol0 >> 6] * LOG2E;
#pragma unroll
    for (int i = 0; i < 2; ++i)
#pragma unroll
      for (int r = 0; r < 4; ++r) {
        float ss = 0.f;
#pragma unroll
        for (int j = 0; j < 4; ++j) ss += acc[i][j][r] * acc[i][j][r];
#pragma unroll
        for (int msk = 1; msk < 16; msk <<= 1) ss += __shfl_xor(ss, msk, 64);
        float scl = tmul / fmaxf(sqrtf(ss), 1e-12f);
#pragma unroll
        for (int j = 0; j < 4; ++j) acc[i][j][r] *= scl;
      }
  }

  if (EPI == 4) {
    __syncthreads();
#pragma unroll
    for (int i = 0; i < 2; ++i)
#pragma unroll
      for (int j = 0; j < 4; ++j)
#pragma unroll
        for (int r = 0; r < 4; ++r) {
          int cl = wc * 64 + j * 16 + li;
          int rl = wr * 32 + i * 16 + g * 4 + r;
          lds[cl * 64 + rl] = cvt_bf16(acc[i][j][r]);
        }
    __syncthreads();
    const int sb = row0 & 2047;
    const int bb = row0 >> 11;
#pragma unroll
    for (int q = 0; q < 4; ++q) {
      int c2 = threadIdx.x * 4 + q;
      int cl = c2 >> 3;
      int s8 = (c2 & 7) * 8;
      int colg = col0 + cl;
      int bh = bb * H_ + (colg >> 6);
      int d  = colg & 63;
      *(bf8*)(Cb + ((size_t)bh * 64 + d) * 2048 + sb + s8) = *(const bf8*)&lds[cl * 64 + s8];
    }
    return;
  }

#pragma unroll
  for (int i = 0; i < 2; ++i)
#pragma unroll
    for (int j = 0; j < 4; ++j)
#pragma unroll
      for (int r = 0; r < 4; ++r) {
        int row = wrow0 + i * 16 + g * 4 + r;
        int col = wcol0 + j * 16 + li;
        if (EPI == 3) Cf[(size_t)row * 768 + col] = acc[i][j][r];
        else          Cb[(size_t)row * 768 + col] = f2bf(acc[i][j][r]);
      }
}

// QKV: 1D grid 2304, XCD row-slice remap; A read DIRECTLY from f32 x.
__global__ __launch_bounds__(256) void gemm_qkv(const float* __restrict__ x,
                                                const u16* __restrict__ Wq, const u16* __restrict__ Wk,
                                                const u16* __restrict__ Wv,
                                                u16* __restrict__ Qb, u16* __restrict__ Kb,
                                                u16* __restrict__ Vt,
                                                const float* __restrict__ temp)
{
  __shared__ __align__(16) u16 lds[192 * 64];
  const int bid  = blockIdx.x;
  const int xcd  = bid & 7;
  const int j    = bid >> 3;
  const int row0 = (xcd * 16 + j / 18) * 64;
  const int rest = j % 18;
  const int z    = rest / 6;
  const int col0 = (rest % 6) * 128;
  if (z == 0)      gemm_core<2, 1>(lds, row0, col0, nullptr, x, Wq, Qb, nullptr, temp);
  else if (z == 1) gemm_core<1, 1>(lds, row0, col0, nullptr, x, Wk, Kb, nullptr, temp);
  else             gemm_core<4, 1>(lds, row0, col0, nullptr, x, Wv, Vt, nullptr, temp);
}

// Output GEMM: 1D grid 768, XCD row-slice remap (A = bf16 attention output).
__global__ __launch_bounds__(256) void gemm_out(const u16* __restrict__ A,
                                                const u16* __restrict__ W,
                                                float* __restrict__ Cf)
{
  __shared__ __align__(16) u16 lds[192 * 64];
  const int bid  = blockIdx.x;
  const int xcd  = bid & 7;
  const int j    = bid >> 3;
  const int row0 = (xcd * 16 + j / 6) * 64;
  const int col0 = (j % 6) * 128;
  gemm_core<3, 0>(lds, row0, col0, A, nullptr, W, nullptr, Cf, nullptr);
}

// Fallback GEMM (W f32 inline-cvt) for !stageW. EPI==0 writes V transposed.
template <int EPI>
__global__ __launch_bounds__(256) void gemm_wf32(const u16* __restrict__ A,
                                                 const float* __restrict__ W,
                                                 u16* __restrict__ Cb,
                                                 float* __restrict__ Cf,
                                                 const float* __restrict__ temp)
{
  const int w  = threadIdx.x >> 6;
  const int ln = threadIdx.x & 63;
  const int li = ln & 15, g = ln >> 4;
  const int wr = w >> 1, wc = w & 1;
  const int row0 = blockIdx.x * 64 + wr * 32;
  const int col0 = blockIdx.y * 128 + wc * 64;

  const u16*   Ap = A + (size_t)(row0 + li) * 768 + g * 8;
  const float* Wp = W + (size_t)(col0 + li) * 768 + g * 8;

  f4 acc[2][4];
#pragma unroll
  for (int i = 0; i < 2; ++i)
#pragma unroll
    for (int j = 0; j < 4; ++j) acc[i][j] = (f4){0.f, 0.f, 0.f, 0.f};

  for (int k = 0; k < 768; k += 32) {
    bf8 a0 = *(const bf8*)(Ap + k);
    bf8 a1 = *(const bf8*)(Ap + (size_t)16 * 768 + k);
    bf8 b0 = ldcvt8(Wp + k);
    bf8 b1 = ldcvt8(Wp + (size_t)16 * 768 + k);
    bf8 b2 = ldcvt8(Wp + (size_t)32 * 768 + k);
    bf8 b3 = ldcvt8(Wp + (size_t)48 * 768 + k);
    acc[0][0] = MFMA_BF16(a0, b0, acc[0][0], 0, 0, 0);
    acc[0][1] = MFMA_BF16(a0, b1, acc[0][1], 0, 0, 0);
    acc[0][2] = MFMA_BF16(a0, b2, acc[0][2], 0, 0, 0);
    acc[0][3] = MFMA_BF16(a0, b3, acc[0][3], 0, 0, 0);
    acc[1][0] = MFMA_BF16(a1, b0, acc[1][0], 0, 0, 0);
    acc[1][1] = MFMA_BF16(a1, b1, acc[1][1], 0, 0, 0);
    acc[1][2] = MFMA_BF16(a1, b2, acc[1][2], 0, 0, 0);
    acc[1][3] = MFMA_BF16(a1, b3, acc[1][3], 0, 0, 0);
  }

  if (EPI == 1 || EPI == 2) {
    float tmul = 1.0f;
    if (EPI == 2) tmul = temp[col0 >> 6] * LOG2E;
#pragma unroll
    for (int i = 0; i < 2; ++i)
#pragma unroll
      for (int r = 0; r < 4; ++r) {
        float ss = 0.f;
#pragma unroll
        for (int j = 0; j < 4; ++j) ss += acc[i][j][r] * acc[i][j][r];
#pragma unroll
        for (int msk = 1; msk < 16; msk <<= 1) ss += __shfl_xor(ss, msk, 64);
        float scl = tmul / fmaxf(sqrtf(ss), 1e-12f);
#pragma unroll
        for (int j = 0; j < 4; ++j) acc[i][j][r] *= scl;
      }
  }

#pragma unroll
  for (int i = 0; i < 2; ++i)
#pragma unroll
    for (int j = 0; j < 4; ++j)
#pragma unroll
      for (int r = 0; r < 4; ++r) {
        int row = row0 + i * 16 + g * 4 + r;
        int col = col0 + j * 16 + li;
        if (EPI == 3)      Cf[(size_t)row * 768 + col] = acc[i][j][r];
        else if (EPI == 0) Cb[((size_t)((row >> 11) * H_ + (col >> 6)) * 64 + (col & 63)) * 2048
                              + (row & 2047)] = f2bf(acc[i][j][r]);
        else               Cb[(size_t)row * 768 + col] = f2bf(acc[i][j][r]);
      }
}

// Flash attention v12 (unchanged from R22, best measured): swapped QK^T,
// in-register P via cvt_pk + ds_bpermute, snake dispatch, QBLK=128, Vt input.
__global__ __launch_bounds__(256, 3) void flash_attn(const u16* __restrict__ Q,
                                                     const u16* __restrict__ K,
                                                     const u16* __restrict__ Vt,
                                                     u16* __restrict__ O,
                                                     const float* __restrict__ temp)
{
  const int bid = blockIdx.x;
  const int xcd = bid & 7;
  const int j   = bid >> 3;
  const int p_  = j & 31, rnd = j >> 5;
  const int pos = (rnd & 1) ? (31 - p_) : p_;
  const int rank = rnd * 32 + pos;
  const int qt  = 15 - rank / 6;
  const int bh  = xcd * 6 + rank % 6;
  const int b = bh / H_, h = bh % H_;
  const size_t base = (size_t)b * S_ * D_ + h * HD_;
  const u16* Qp  = Q + base;
  const u16* Kp  = K + base;
  const u16* Vtp = Vt + (size_t)bh * 64 * 2048;
  u16*       Op  = O + base;

  const float C2 = fabsf(temp[h]) * LOG2E;

  const int w  = threadIdx.x >> 6;
  const int ln = threadIdx.x & 63;
  const int li = ln & 15, g = ln >> 4;

  __shared__ __align__(16) u16 k_lds[64][72];
  __shared__ __align__(16) u16 vt[64][72];

  const int q0 = qt * 128;

  bf8 qf[2][2];
#pragma unroll
  for (int i = 0; i < 2; ++i) {
    const u16* qp = Qp + (size_t)(q0 + w * 32 + i * 16 + li) * D_;
    qf[i][0] = *(const bf8*)(qp + g * 8);
    qf[i][1] = *(const bf8*)(qp + 32 + g * 8);
  }

  const int r2 = (threadIdx.x >> 3) * 2;
  const int c0 = (threadIdx.x & 7) * 8;
  const u16* ksrc = Kp  + (size_t)r2 * D_ + c0;
  const u16* vsrc = Vtp + (size_t)r2 * 2048 + c0;

  bf8 ka = *(const bf8*)(ksrc);
  bf8 kb = *(const bf8*)(ksrc + D_);
  bf8 va = *(const bf8*)(vsrc);
  bf8 vb_ = *(const bf8*)(vsrc + 2048);

  f4 o[2][4];
  float lp[2] = {0.f, 0.f};
#pragma unroll
  for (int i = 0; i < 2; ++i)
#pragma unroll
    for (int c = 0; c < 4; ++c) o[i][c] = (f4){0.f, 0.f, 0.f, 0.f};

  const int addrA = (((g & 1) << 5) + li) << 2;
  const int addrB = addrA + 64;
  const int ghi   = g >> 1;

  const int nt = 2 * qt + 1;
  for (int kt = 0; kt <= nt; ++kt) {
    __syncthreads();
    {
      *(bf8*)&k_lds[r2][c0]     = ka;
      *(bf8*)&k_lds[r2 + 1][c0] = kb;
      *(bf8*)&vt[r2][c0]        = va;
      *(bf8*)&vt[r2 + 1][c0]    = vb_;
    }
    if (kt < nt) {
      const u16* ks = ksrc + (size_t)(kt + 1) * 64 * D_;
      const u16* vs = vsrc + (kt + 1) * 64;
      ka  = *(const bf8*)(ks);
      kb  = *(const bf8*)(ks + D_);
      va  = *(const bf8*)(vs);
      vb_ = *(const bf8*)(vs + 2048);
    }
    asm volatile("s_waitcnt lgkmcnt(0)" ::: "memory");
    __builtin_amdgcn_s_barrier();

    f4 sc[4][2];
#pragma unroll
    for (int kb2 = 0; kb2 < 4; ++kb2) {
      sc[kb2][0] = (f4){0.f, 0.f, 0.f, 0.f};
      sc[kb2][1] = (f4){0.f, 0.f, 0.f, 0.f};
      bf8 k0 = *(const bf8*)&k_lds[kb2 * 16 + li][g * 8];
      bf8 k1 = *(const bf8*)&k_lds[kb2 * 16 + li][32 + g * 8];
      sc[kb2][0] = MFMA_BF16(k0, qf[0][0], sc[kb2][0], 0, 0, 0);
      sc[kb2][0] = MFMA_BF16(k1, qf[0][1], sc[kb2][0], 0, 0, 0);
      sc[kb2][1] = MFMA_BF16(k0, qf[1][0], sc[kb2][1], 0, 0, 0);
      sc[kb2][1] = MFMA_BF16(k1, qf[1][1], sc[kb2][1], 0, 0, 0);
    }

    if (kt >= 2 * qt) {
#pragma unroll
      for (int kb2 = 0; kb2 < 4; ++kb2)
#pragma unroll
        for (int qb = 0; qb < 2; ++qb)
#pragma unroll
          for (int r = 0; r < 4; ++r) {
            int key  = kt * 64 + kb2 * 16 + g * 4 + r;
            int qrow = q0 + w * 32 + qb * 16 + li;
            if (key > qrow) sc[kb2][qb][r] = -__builtin_inff();
          }
    }

    u32 pkv[2][4][2];
#pragma unroll
    for (int qb = 0; qb < 2; ++qb)
#pragma unroll
      for (int kb2 = 0; kb2 < 4; ++kb2) {
        float p0 = exp2_raw(sc[kb2][qb][0] - C2);
        float p1 = exp2_raw(sc[kb2][qb][1] - C2);
        float p2 = exp2_raw(sc[kb2][qb][2] - C2);
        float p3 = exp2_raw(sc[kb2][qb][3] - C2);
        lp[qb] += (p0 + p1) + (p2 + p3);
        pkv[qb][kb2][0] = cvt_pk2(p0, p1);
        pkv[qb][kb2][1] = cvt_pk2(p2, p3);
      }

#pragma unroll
    for (int ks = 0; ks < 2; ++ks) {
#pragma unroll
      for (int qb = 0; qb < 2; ++qb) {
        int e = 2 * ks, o1 = 2 * ks + 1;
        u32 a0 = (u32)__builtin_amdgcn_ds_bpermute(addrA, (int)pkv[qb][e][0]);
        u32 b0 = (u32)__builtin_amdgcn_ds_bpermute(addrA, (int)pkv[qb][o1][0]);
        u32 a1 = (u32)__builtin_amdgcn_ds_bpermute(addrA, (int)pkv[qb][e][1]);
        u32 b1 = (u32)__builtin_amdgcn_ds_bpermute(addrA, (int)pkv[qb][o1][1]);
        u32 a2 = (u32)__builtin_amdgcn_ds_bpermute(addrB, (int)pkv[qb][e][0]);
        u32 b2 = (u32)__builtin_amdgcn_ds_bpermute(addrB, (int)pkv[qb][o1][0]);
        u32 a3 = (u32)__builtin_amdgcn_ds_bpermute(addrB, (int)pkv[qb][e][1]);
        u32 b3 = (u32)__builtin_amdgcn_ds_bpermute(addrB, (int)pkv[qb][o1][1]);
        union { u32 u[4]; bf8 v; } pa;
        pa.u[0] = ghi ? b0 : a0;
        pa.u[1] = ghi ? b1 : a1;
        pa.u[2] = ghi ? b2 : a2;
        pa.u[3] = ghi ? b3 : a3;
#pragma unroll
        for (int c = 0; c < 4; ++c) {
          bf8 vv = *(const bf8*)&vt[c * 16 + li][ks * 32 + g * 8];
          o[qb][c] = MFMA_BF16(pa.v, vv, o[qb][c], 0, 0, 0);
        }
      }
    }
  }

  float linv[2][4];
#pragma unroll
  for (int qb = 0; qb < 2; ++qb) {
    float t = lp[qb];
    t += __shfl_xor(t, 16, 64);
    t += __shfl_xor(t, 32, 64);
    union { float f; int i; } ci; ci.f = t;
#pragma unroll
    for (int r = 0; r < 4; ++r) {
      int src = (g * 4 + r) << 2;
      union { int i; float f; } cv;
      cv.i = __builtin_amdgcn_ds_bpermute(src, ci.i);
      linv[qb][r] = 1.0f / cv.f;
    }
  }
#pragma unroll
  for (int qb = 0; qb < 2; ++qb)
#pragma unroll
    for (int c = 0; c < 4; ++c)
#pragma unroll
      for (int r = 0; r < 4; ++r) {
        int row = q0 + w * 32 + qb * 16 + g * 4 + r;
        Op[(size_t)row * D_ + c * 16 + li] = cvt_bf16(o[qb][c][r] * linv[qb][r]);
      }
}

extern "C" void kernel_launch(void* const* d_in, const int* in_sizes, int n_in,
                              void* d_out, int out_size, void* d_ws, size_t ws_size,
                              hipStream_t stream) {
  const void *xv, *Wqv, *Wkv, *Wvv, *Wov, *tv;
  if (in_sizes[0] == M_ * D_) {
    xv = d_in[0]; Wqv = d_in[1]; Wkv = d_in[2]; Wvv = d_in[3]; Wov = d_in[4]; tv = d_in[5];
  } else {
    Wkv = d_in[0]; Wov = d_in[1]; Wqv = d_in[2]; Wvv = d_in[3]; tv = d_in[4]; xv = d_in[5];
  }
  const float* x    = (const float*)xv;
  const float* Wq   = (const float*)Wqv;
  const float* Wk   = (const float*)Wkv;
  const float* Wv   = (const float*)Wvv;
  const float* Wo   = (const float*)Wov;
  const float* temp = (const float*)tv;

  const size_t SZ  = (size_t)M_ * D_;   // 6291456
  const size_t WSZ = (size_t)D_ * D_;   // 589824
  u16* ws = (u16*)d_ws;
  u16* Qb = ws;
  u16* Kb = ws + SZ;
  u16* Vt = ws + 2 * SZ;   // transposed V: [48 bh][64 d][2048 s]

  const bool stageW = ws_size >= (3 * SZ + 4 * WSZ) * sizeof(u16);
  u16* Wqb = ws + 3 * SZ;
  u16* Wkb = Wqb + WSZ;
  u16* Wvb = Wkb + WSZ;
  u16* Wob = Wvb + WSZ;

  if (stageW) {
    stage_w4<<<dim3(192, 4), 256, 0, stream>>>(Wq, Wk, Wv, Wo,
                                               Wqb, Wkb, Wvb, Wob, (int)(WSZ / 4));
    gemm_qkv<<<2304, 256, 0, stream>>>(x, Wqb, Wkb, Wvb, Qb, Kb, Vt, temp);
    flash_attn<<<768, 256, 0, stream>>>(Qb, Kb, Vt, Qb, temp);
    gemm_out<<<768, 256, 0, stream>>>(Qb, Wob, (float*)d_out);
  } else {
    dim3 gg(M_ / 64, D_ / 128), bb(256);
    u16* XB = (u16*)d_out;   // fallback: stage bf16(x) in d_out
    stage_cvt<<<2048, 256, 0, stream>>>(x, XB, (int)(SZ / 4));
    gemm_wf32<2><<<gg, bb, 0, stream>>>(XB, Wq, Qb, nullptr, temp);
    gemm_wf32<1><<<gg, bb, 0, stream>>>(XB, Wk, Kb, nullptr, temp);
    gemm_wf32<0><<<gg, bb, 0, stream>>>(XB, Wv, Vt, nullptr, temp);
    flash_attn<<<768, 256, 0, stream>>>(Qb, Kb, Vt, Qb, temp);
    gemm_wf32<3><<<gg, bb, 0, stream>>>(Qb, Wo, nullptr, (float*)d_out, temp);
  }
}

// Round 25
// 124.413 us; speedup vs baseline: 1.0952x; 1.0952x over previous
//
#include <hip/hip_runtime.h>
#include <hip/hip_bf16.h>

#define B_ 4
#define S_ 2048
#define D_ 768
#define H_ 12
#define HD_ 64
#define M_ (B_*S_)   // 8192
#define LOG2E 1.44269504088896f

typedef __attribute__((ext_vector_type(8))) short bf8;
typedef __attribute__((ext_vector_type(4))) float f4;
typedef unsigned short u16;
typedef unsigned int   u32;

typedef __attribute__((address_space(3))) u32 lds_u32;
typedef __attribute__((address_space(1))) const u32 glob_u32;

__device__ __forceinline__ float bf2f(u16 u) {
  union { u32 i; float f; } c; c.i = ((u32)u) << 16; return c.f;
}
__device__ __forceinline__ u16 f2bf(float x) {
  union { float f; u32 i; } c; c.f = x;
  u32 r = (c.i + 0x7FFFu + ((c.i >> 16) & 1u)) >> 16;
  return (u16)r;
}
__device__ __forceinline__ u16 cvt_bf16(float x) {
  u32 r;
  asm("v_cvt_pk_bf16_f32 %0, %1, %1" : "=v"(r) : "v"(x));
  return (u16)r;
}
__device__ __forceinline__ u32 cvt_pk2(float lo, float hi) {
  u32 r;
  asm("v_cvt_pk_bf16_f32 %0, %1, %2" : "=v"(r) : "v"(lo), "v"(hi));
  return r;
}
__device__ __forceinline__ float exp2_raw(float x) {
  float r;
  asm("v_exp_f32 %0, %1" : "=v"(r) : "v"(x));
  return r;
}
__device__ __forceinline__ void glds16(const u16* g, u16* l) {
  __builtin_amdgcn_global_load_lds((glob_u32*)g, (lds_u32*)l, 16, 0, 0);
}

// Stage x + 4 weights f32 -> bf16 in ONE launch (blockIdx.y selects tensor).
__global__ __launch_bounds__(256) void stage_all(const float* __restrict__ x,
                                                 const float* __restrict__ w0, const float* __restrict__ w1,
                                                 const float* __restrict__ w2, const float* __restrict__ w3,
                                                 u16* __restrict__ xo,
                                                 u16* __restrict__ o0, u16* __restrict__ o1,
                                                 u16* __restrict__ o2, u16* __restrict__ o3,
                                                 int nx4, int nw4)
{
  int y = blockIdx.y;
  const float* src = (y == 0) ? x : (y == 1) ? w0 : (y == 2) ? w1 : (y == 3) ? w2 : w3;
  u16*         dst = (y == 0) ? xo : (y == 1) ? o0 : (y == 2) ? o1 : (y == 3) ? o2 : o3;
  int n4 = (y == 0) ? nx4 : nw4;
  for (int i = blockIdx.x * blockDim.x + threadIdx.x; i < n4; i += gridDim.x * blockDim.x) {
    float4 v = ((const float4*)src)[i];
    ushort4 o;
    o.x = f2bf(v.x); o.y = f2bf(v.y); o.z = f2bf(v.z); o.w = f2bf(v.w);
    ((ushort4*)dst)[i] = o;
  }
}

// f32 -> bf16 (fallback x staging)
__global__ __launch_bounds__(256) void stage_cvt(const float* __restrict__ in,
                                                 u16* __restrict__ out, int n4)
{
  for (int i = blockIdx.x * blockDim.x + threadIdx.x; i < n4; i += gridDim.x * blockDim.x) {
    float4 v = ((const float4*)in)[i];
    ushort4 o;
    o.x = f2bf(v.x); o.y = f2bf(v.y); o.z = f2bf(v.z); o.w = f2bf(v.w);
    ((ushort4*)out)[i] = o;
  }
}

__device__ __forceinline__ bf8 ldcvt8(const float* __restrict__ p) {
  float4 a = *(const float4*)p;
  float4 b = *(const float4*)(p + 4);
  bf8 r;
  r[0] = f2bf(a.x); r[1] = f2bf(a.y); r[2] = f2bf(a.z); r[3] = f2bf(a.w);
  r[4] = f2bf(b.x); r[5] = f2bf(b.y); r[6] = f2bf(b.z); r[7] = f2bf(b.w);
  return r;
}

#define MFMA_BF16 __builtin_amdgcn_mfma_f32_16x16x32_bf16

// GEMM v4 core (R22 winner, restored): tile 64x128, BK=64, glds16(16B) into
// linear LDS w/ both-sides XOR chunk swizzle.
// EPI: 0 bf16; 1 head-L2-norm; 2 norm*temp[h]*log2e; 3 f32; 4 V-transposed.
template <int EPI>
__device__ __forceinline__ void gemm_core(u16* lds, int row0, int col0,
                                          const u16* __restrict__ A,
                                          const u16* __restrict__ W,
                                          u16* __restrict__ Cb,
                                          float* __restrict__ Cf,
                                          const float* __restrict__ temp)
{
  u16* a_lds = lds;
  u16* b_lds = lds + 64 * 64;

  const int w  = threadIdx.x >> 6;
  const int ln = threadIdx.x & 63;
  const int li = ln & 15, g = ln >> 4;
  const int wr = w >> 1, wc = w & 1;

  const int srow = ln >> 3;
  const int scol = ((ln & 7) ^ srow) * 8;
  const u16* Abase = A + (size_t)(row0 + srow) * 768 + scol;
  const u16* Bbase = W + (size_t)(col0 + srow) * 768 + scol;

  f4 acc[2][4];
#pragma unroll
  for (int i = 0; i < 2; ++i)
#pragma unroll
    for (int j = 0; j < 4; ++j) acc[i][j] = (f4){0.f, 0.f, 0.f, 0.f};

  for (int kt = 0; kt < 12; ++kt) {
    const int k0 = kt * 64;
#pragma unroll
    for (int i = 0; i < 2; ++i) {
      int seg = w * 2 + i;
      glds16(Abase + (size_t)(seg * 8) * 768 + k0, a_lds + seg * 512);
    }
#pragma unroll
    for (int i = 0; i < 4; ++i) {
      int seg = w * 4 + i;
      glds16(Bbase + (size_t)(seg * 8) * 768 + k0, b_lds + seg * 512);
    }
    asm volatile("s_waitcnt vmcnt(0)" ::: "memory");
    __syncthreads();

#pragma unroll
    for (int kk = 0; kk < 2; ++kk) {
      const int co = (((kk * 4 + g) ^ (li & 7)) * 8);
      bf8 a0 = *(const bf8*)(a_lds + (wr * 32 + li) * 64 + co);
      bf8 a1 = *(const bf8*)(a_lds + (wr * 32 + 16 + li) * 64 + co);
      bf8 b0 = *(const bf8*)(b_lds + (wc * 64 + li) * 64 + co);
      bf8 b1 = *(const bf8*)(b_lds + (wc * 64 + 16 + li) * 64 + co);
      bf8 b2 = *(const bf8*)(b_lds + (wc * 64 + 32 + li) * 64 + co);
      bf8 b3 = *(const bf8*)(b_lds + (wc * 64 + 48 + li) * 64 + co);
      acc[0][0] = MFMA_BF16(a0, b0, acc[0][0], 0, 0, 0);
      acc[0][1] = MFMA_BF16(a0, b1, acc[0][1], 0, 0, 0);
      acc[0][2] = MFMA_BF16(a0, b2, acc[0][2], 0, 0, 0);
      acc[0][3] = MFMA_BF16(a0, b3, acc[0][3], 0, 0, 0);
      acc[1][0] = MFMA_BF16(a1, b0, acc[1][0], 0, 0, 0);
      acc[1][1] = MFMA_BF16(a1, b1, acc[1][1], 0, 0, 0);
      acc[1][2] = MFMA_BF16(a1, b2, acc[1][2], 0, 0, 0);
      acc[1][3] = MFMA_BF16(a1, b3, acc[1][3], 0, 0, 0);
    }
    __syncthreads();
  }

  const int wrow0 = row0 + wr * 32;
  const int wcol0 = col0 + wc * 64;

  if (EPI == 1 || EPI == 2) {
    float tmul = 1.0f;
    if (EPI == 2) tmul = temp[wcol0 >> 6] * LOG2E;
#pragma unroll
    for (int i = 0; i < 2; ++i)
#pragma unroll
      for (int r = 0; r < 4; ++r) {
        float ss = 0.f;
#pragma unroll
        for (int j = 0; j < 4; ++j) ss += acc[i][j][r] * acc[i][j][r];
#pragma unroll
        for (int msk = 1; msk < 16; msk <<= 1) ss += __shfl_xor(ss, msk, 64);
        float scl = tmul / fmaxf(sqrtf(ss), 1e-12f);
#pragma unroll
        for (int j = 0; j < 4; ++j) acc[i][j][r] *= scl;
      }
  }

  if (EPI == 4) {
    __syncthreads();
#pragma unroll
    for (int i = 0; i < 2; ++i)
#pragma unroll
      for (int j = 0; j < 4; ++j)
#pragma unroll
        for (int r = 0; r < 4; ++r) {
          int cl = wc * 64 + j * 16 + li;
          int rl = wr * 32 + i * 16 + g * 4 + r;
          lds[cl * 64 + rl] = cvt_bf16(acc[i][j][r]);
        }
    __syncthreads();
    const int sb = row0 & 2047;
    const int bb = row0 >> 11;
#pragma unroll
    for (int q = 0; q < 4; ++q) {
      int c2 = threadIdx.x * 4 + q;
      int cl = c2 >> 3;
      int s8 = (c2 & 7) * 8;
      int colg = col0 + cl;
      int bh = bb * H_ + (colg >> 6);
      int d  = colg & 63;
      *(bf8*)(Cb + ((size_t)bh * 64 + d) * 2048 + sb + s8) = *(const bf8*)&lds[cl * 64 + s8];
    }
    return;
  }

#pragma unroll
  for (int i = 0; i < 2; ++i)
#pragma unroll
    for (int j = 0; j < 4; ++j)
#pragma unroll
      for (int r = 0; r < 4; ++r) {
        int row = wrow0 + i * 16 + g * 4 + r;
        int col = wcol0 + j * 16 + li;
        if (EPI == 3) Cf[(size_t)row * 768 + col] = acc[i][j][r];
        else          Cb[(size_t)row * 768 + col] = f2bf(acc[i][j][r]);
      }
}

// QKV: 1D grid 2304, XCD row-slice remap. z==2 (V) writes TRANSPOSED Vt.
__global__ __launch_bounds__(256) void gemm_qkv(const u16* __restrict__ XB,
                                                const u16* __restrict__ Wq, const u16* __restrict__ Wk,
                                                const u16* __restrict__ Wv,
                                                u16* __restrict__ Qb, u16* __restrict__ Kb,
                                                u16* __restrict__ Vt,
                                                const float* __restrict__ temp)
{
  __shared__ __align__(16) u16 lds[192 * 64];
  const int bid  = blockIdx.x;
  const int xcd  = bid & 7;
  const int j    = bid >> 3;
  const int row0 = (xcd * 16 + j / 18) * 64;
  const int rest = j % 18;
  const int z    = rest / 6;
  const int col0 = (rest % 6) * 128;
  if (z == 0)      gemm_core<2>(lds, row0, col0, XB, Wq, Qb, nullptr, temp);
  else if (z == 1) gemm_core<1>(lds, row0, col0, XB, Wk, Kb, nullptr, temp);
  else             gemm_core<4>(lds, row0, col0, XB, Wv, Vt, nullptr, temp);
}

// Output GEMM: 1D grid 768, XCD row-slice remap.
__global__ __launch_bounds__(256) void gemm_out(const u16* __restrict__ A,
                                                const u16* __restrict__ W,
                                                float* __restrict__ Cf)
{
  __shared__ __align__(16) u16 lds[192 * 64];
  const int bid  = blockIdx.x;
  const int xcd  = bid & 7;
  const int j    = bid >> 3;
  const int row0 = (xcd * 16 + j / 6) * 64;
  const int col0 = (j % 6) * 128;
  gemm_core<3>(lds, row0, col0, A, W, nullptr, Cf, nullptr);
}

// Fallback GEMM (W f32 inline-cvt) for !stageW. EPI==0 writes V transposed.
template <int EPI>
__global__ __launch_bounds__(256) void gemm_wf32(const u16* __restrict__ A,
                                                 const float* __restrict__ W,
                                                 u16* __restrict__ Cb,
                                                 float* __restrict__ Cf,
                                                 const float* __restrict__ temp)
{
  const int w  = threadIdx.x >> 6;
  const int ln = threadIdx.x & 63;
  const int li = ln & 15, g = ln >> 4;
  const int wr = w >> 1, wc = w & 1;
  const int row0 = blockIdx.x * 64 + wr * 32;
  const int col0 = blockIdx.y * 128 + wc * 64;

  const u16*   Ap = A + (size_t)(row0 + li) * 768 + g * 8;
  const float* Wp = W + (size_t)(col0 + li) * 768 + g * 8;

  f4 acc[2][4];
#pragma unroll
  for (int i = 0; i < 2; ++i)
#pragma unroll
    for (int j = 0; j < 4; ++j) acc[i][j] = (f4){0.f, 0.f, 0.f, 0.f};

  for (int k = 0; k < 768; k += 32) {
    bf8 a0 = *(const bf8*)(Ap + k);
    bf8 a1 = *(const bf8*)(Ap + (size_t)16 * 768 + k);
    bf8 b0 = ldcvt8(Wp + k);
    bf8 b1 = ldcvt8(Wp + (size_t)16 * 768 + k);
    bf8 b2 = ldcvt8(Wp + (size_t)32 * 768 + k);
    bf8 b3 = ldcvt8(Wp + (size_t)48 * 768 + k);
    acc[0][0] = MFMA_BF16(a0, b0, acc[0][0], 0, 0, 0);
    acc[0][1] = MFMA_BF16(a0, b1, acc[0][1], 0, 0, 0);
    acc[0][2] = MFMA_BF16(a0, b2, acc[0][2], 0, 0, 0);
    acc[0][3] = MFMA_BF16(a0, b3, acc[0][3], 0, 0, 0);
    acc[1][0] = MFMA_BF16(a1, b0, acc[1][0], 0, 0, 0);
    acc[1][1] = MFMA_BF16(a1, b1, acc[1][1], 0, 0, 0);
    acc[1][2] = MFMA_BF16(a1, b2, acc[1][2], 0, 0, 0);
    acc[1][3] = MFMA_BF16(a1, b3, acc[1][3], 0, 0, 0);
  }

  if (EPI == 1 || EPI == 2) {
    float tmul = 1.0f;
    if (EPI == 2) tmul = temp[col0 >> 6] * LOG2E;
#pragma unroll
    for (int i = 0; i < 2; ++i)
#pragma unroll
      for (int r = 0; r < 4; ++r) {
        float ss = 0.f;
#pragma unroll
        for (int j = 0; j < 4; ++j) ss += acc[i][j][r] * acc[i][j][r];
#pragma unroll
        for (int msk = 1; msk < 16; msk <<= 1) ss += __shfl_xor(ss, msk, 64);
        float scl = tmul / fmaxf(sqrtf(ss), 1e-12f);
#pragma unroll
        for (int j = 0; j < 4; ++j) acc[i][j][r] *= scl;
      }
  }

#pragma unroll
  for (int i = 0; i < 2; ++i)
#pragma unroll
    for (int j = 0; j < 4; ++j)
#pragma unroll
      for (int r = 0; r < 4; ++r) {
        int row = row0 + i * 16 + g * 4 + r;
        int col = col0 + j * 16 + li;
        if (EPI == 3)      Cf[(size_t)row * 768 + col] = acc[i][j][r];
        else if (EPI == 0) Cb[((size_t)((row >> 11) * H_ + (col >> 6)) * 64 + (col & 63)) * 2048
                              + (row & 2047)] = f2bf(acc[i][j][r]);
        else               Cb[(size_t)row * 768 + col] = f2bf(acc[i][j][r]);
      }
}

// Flash attention v13: v12 + DOUBLE-BUFFERED K/V LDS (one barrier per tile).
// Iteration kt writes buf[kt&1]; all readers of that buffer finished before
// the previous barrier (program order: compute -> write -> barrier), so a
// single barrier per iteration is race-free. Swapped QK^T, in-register P via
// cvt_pk + ds_bpermute, snake dispatch, QBLK=128, pre-transposed Vt.
__global__ __launch_bounds__(256, 3) void flash_attn(const u16* __restrict__ Q,
                                                     const u16* __restrict__ K,
                                                     const u16* __restrict__ Vt,
                                                     u16* __restrict__ O,
                                                     const float* __restrict__ temp)
{
  const int bid = blockIdx.x;
  const int xcd = bid & 7;
  const int j   = bid >> 3;
  const int p_  = j & 31, rnd = j >> 5;
  const int pos = (rnd & 1) ? (31 - p_) : p_;
  const int rank = rnd * 32 + pos;
  const int qt  = 15 - rank / 6;
  const int bh  = xcd * 6 + rank % 6;
  const int b = bh / H_, h = bh % H_;
  const size_t base = (size_t)b * S_ * D_ + h * HD_;
  const u16* Qp  = Q + base;
  const u16* Kp  = K + base;
  const u16* Vtp = Vt + (size_t)bh * 64 * 2048;
  u16*       Op  = O + base;

  const float C2 = fabsf(temp[h]) * LOG2E;

  const int w  = threadIdx.x >> 6;
  const int ln = threadIdx.x & 63;
  const int li = ln & 15, g = ln >> 4;

  __shared__ __align__(16) u16 k_lds[2][64][72];
  __shared__ __align__(16) u16 vt[2][64][72];

  const int q0 = qt * 128;

  bf8 qf[2][2];
#pragma unroll
  for (int i = 0; i < 2; ++i) {
    const u16* qp = Qp + (size_t)(q0 + w * 32 + i * 16 + li) * D_;
    qf[i][0] = *(const bf8*)(qp + g * 8);
    qf[i][1] = *(const bf8*)(qp + 32 + g * 8);
  }

  const int r2 = (threadIdx.x >> 3) * 2;
  const int c0 = (threadIdx.x & 7) * 8;
  const u16* ksrc = Kp  + (size_t)r2 * D_ + c0;
  const u16* vsrc = Vtp + (size_t)r2 * 2048 + c0;

  bf8 ka = *(const bf8*)(ksrc);
  bf8 kb = *(const bf8*)(ksrc + D_);
  bf8 va = *(const bf8*)(vsrc);
  bf8 vb_ = *(const bf8*)(vsrc + 2048);

  f4 o[2][4];
  float lp[2] = {0.f, 0.f};
#pragma unroll
  for (int i = 0; i < 2; ++i)
#pragma unroll
    for (int c = 0; c < 4; ++c) o[i][c] = (f4){0.f, 0.f, 0.f, 0.f};

  const int addrA = (((g & 1) << 5) + li) << 2;
  const int addrB = addrA + 64;
  const int ghi   = g >> 1;

  const int nt = 2 * qt + 1;
  for (int kt = 0; kt <= nt; ++kt) {
    const int cur = kt & 1;
    {
      *(bf8*)&k_lds[cur][r2][c0]     = ka;
      *(bf8*)&k_lds[cur][r2 + 1][c0] = kb;
      *(bf8*)&vt[cur][r2][c0]        = va;
      *(bf8*)&vt[cur][r2 + 1][c0]    = vb_;
    }
    if (kt < nt) {
      const u16* ks = ksrc + (size_t)(kt + 1) * 64 * D_;
      const u16* vs = vsrc + (kt + 1) * 64;
      ka  = *(const bf8*)(ks);
      kb  = *(const bf8*)(ks + D_);
      va  = *(const bf8*)(vs);
      vb_ = *(const bf8*)(vs + 2048);
    }
    asm volatile("s_waitcnt lgkmcnt(0)" ::: "memory");
    __builtin_amdgcn_s_barrier();   // single barrier per tile (double-buffered)

    f4 sc[4][2];
#pragma unroll
    for (int kb2 = 0; kb2 < 4; ++kb2) {
      sc[kb2][0] = (f4){0.f, 0.f, 0.f, 0.f};
      sc[kb2][1] = (f4){0.f, 0.f, 0.f, 0.f};
      bf8 k0 = *(const bf8*)&k_lds[cur][kb2 * 16 + li][g * 8];
      bf8 k1 = *(const bf8*)&k_lds[cur][kb2 * 16 + li][32 + g * 8];
      sc[kb2][0] = MFMA_BF16(k0, qf[0][0], sc[kb2][0], 0, 0, 0);
      sc[kb2][0] = MFMA_BF16(k1, qf[0][1], sc[kb2][0], 0, 0, 0);
      sc[kb2][1] = MFMA_BF16(k0, qf[1][0], sc[kb2][1], 0, 0, 0);
      sc[kb2][1] = MFMA_BF16(k1, qf[1][1], sc[kb2][1], 0, 0, 0);
    }

    if (kt >= 2 * qt) {
#pragma unroll
      for (int kb2 = 0; kb2 < 4; ++kb2)
#pragma unroll
        for (int qb = 0; qb < 2; ++qb)
#pragma unroll
          for (int r = 0; r < 4; ++r) {
            int key  = kt * 64 + kb2 * 16 + g * 4 + r;
            int qrow = q0 + w * 32 + qb * 16 + li;
            if (key > qrow) sc[kb2][qb][r] = -__builtin_inff();
          }
    }

    u32 pkv[2][4][2];
#pragma unroll
    for (int qb = 0; qb < 2; ++qb)
#pragma unroll
      for (int kb2 = 0; kb2 < 4; ++kb2) {
        float p0 = exp2_raw(sc[kb2][qb][0] - C2);
        float p1 = exp2_raw(sc[kb2][qb][1] - C2);
        float p2 = exp2_raw(sc[kb2][qb][2] - C2);
        float p3 = exp2_raw(sc[kb2][qb][3] - C2);
        lp[qb] += (p0 + p1) + (p2 + p3);
        pkv[qb][kb2][0] = cvt_pk2(p0, p1);
        pkv[qb][kb2][1] = cvt_pk2(p2, p3);
      }

#pragma unroll
    for (int ks = 0; ks < 2; ++ks) {
#pragma unroll
      for (int qb = 0; qb < 2; ++qb) {
        int e = 2 * ks, o1 = 2 * ks + 1;
        u32 a0 = (u32)__builtin_amdgcn_ds_bpermute(addrA, (int)pkv[qb][e][0]);
        u32 b0 = (u32)__builtin_amdgcn_ds_bpermute(addrA, (int)pkv[qb][o1][0]);
        u32 a1 = (u32)__builtin_amdgcn_ds_bpermute(addrA, (int)pkv[qb][e][1]);
        u32 b1 = (u32)__builtin_amdgcn_ds_bpermute(addrA, (int)pkv[qb][o1][1]);
        u32 a2 = (u32)__builtin_amdgcn_ds_bpermute(addrB, (int)pkv[qb][e][0]);
        u32 b2 = (u32)__builtin_amdgcn_ds_bpermute(addrB, (int)pkv[qb][o1][0]);
        u32 a3 = (u32)__builtin_amdgcn_ds_bpermute(addrB, (int)pkv[qb][e][1]);
        u32 b3 = (u32)__builtin_amdgcn_ds_bpermute(addrB, (int)pkv[qb][o1][1]);
        union { u32 u[4]; bf8 v; } pa;
        pa.u[0] = ghi ? b0 : a0;
        pa.u[1] = ghi ? b1 : a1;
        pa.u[2] = ghi ? b2 : a2;
        pa.u[3] = ghi ? b3 : a3;
#pragma unroll
        for (int c = 0; c < 4; ++c) {
          bf8 vv = *(const bf8*)&vt[cur][c * 16 + li][ks * 32 + g * 8];
          o[qb][c] = MFMA_BF16(pa.v, vv, o[qb][c], 0, 0, 0);
        }
      }
    }
  }

  float linv[2][4];
#pragma unroll
  for (int qb = 0; qb < 2; ++qb) {
    float t = lp[qb];
    t += __shfl_xor(t, 16, 64);
    t += __shfl_xor(t, 32, 64);
    union { float f; int i; } ci; ci.f = t;
#pragma unroll
    for (int r = 0; r < 4; ++r) {
      int src = (g * 4 + r) << 2;
      union { int i; float f; } cv;
      cv.i = __builtin_amdgcn_ds_bpermute(src, ci.i);
      linv[qb][r] = 1.0f / cv.f;
    }
  }
#pragma unroll
  for (int qb = 0; qb < 2; ++qb)
#pragma unroll
    for (int c = 0; c < 4; ++c)
#pragma unroll
      for (int r = 0; r < 4; ++r) {
        int row = q0 + w * 32 + qb * 16 + g * 4 + r;
        Op[(size_t)row * D_ + c * 16 + li] = cvt_bf16(o[qb][c][r] * linv[qb][r]);
      }
}

extern "C" void kernel_launch(void* const* d_in, const int* in_sizes, int n_in,
                              void* d_out, int out_size, void* d_ws, size_t ws_size,
                              hipStream_t stream) {
  const void *xv, *Wqv, *Wkv, *Wvv, *Wov, *tv;
  if (in_sizes[0] == M_ * D_) {
    xv = d_in[0]; Wqv = d_in[1]; Wkv = d_in[2]; Wvv = d_in[3]; Wov = d_in[4]; tv = d_in[5];
  } else {
    Wkv = d_in[0]; Wov = d_in[1]; Wqv = d_in[2]; Wvv = d_in[3]; tv = d_in[4]; xv = d_in[5];
  }
  const float* x    = (const float*)xv;
  const float* Wq   = (const float*)Wqv;
  const float* Wk   = (const float*)Wkv;
  const float* Wv   = (const float*)Wvv;
  const float* Wo   = (const float*)Wov;
  const float* temp = (const float*)tv;

  const size_t SZ  = (size_t)M_ * D_;   // 6291456
  const size_t WSZ = (size_t)D_ * D_;   // 589824
  u16* ws = (u16*)d_ws;
  u16* Qb = ws;
  u16* Kb = ws + SZ;
  u16* Vt = ws + 2 * SZ;   // transposed V: [48 bh][64 d][2048 s]
  u16* XB = (u16*)d_out;   // bf16(x) staged in d_out (scratch until final GEMM)

  const bool stageW = ws_size >= (3 * SZ + 4 * WSZ) * sizeof(u16);
  u16* Wqb = ws + 3 * SZ;
  u16* Wkb = Wqb + WSZ;
  u16* Wvb = Wkb + WSZ;
  u16* Wob = Wvb + WSZ;

  if (stageW) {
    stage_all<<<dim3(512, 5), 256, 0, stream>>>(x, Wq, Wk, Wv, Wo,
                                                XB, Wqb, Wkb, Wvb, Wob,
                                                (int)(SZ / 4), (int)(WSZ / 4));
    gemm_qkv<<<2304, 256, 0, stream>>>(XB, Wqb, Wkb, Wvb, Qb, Kb, Vt, temp);
    flash_attn<<<768, 256, 0, stream>>>(Qb, Kb, Vt, Qb, temp);
    gemm_out<<<768, 256, 0, stream>>>(Qb, Wob, (float*)d_out);
  } else {
    dim3 gg(M_ / 64, D_ / 128), bb(256);
    u16* XB2 = (u16*)d_out;
    stage_cvt<<<2048, 256, 0, stream>>>(x, XB2, (int)(SZ / 4));
    gemm_wf32<2><<<gg, bb, 0, stream>>>(XB2, Wq, Qb, nullptr, temp);
    gemm_wf32<1><<<gg, bb, 0, stream>>>(XB2, Wk, Kb, nullptr, temp);
    gemm_wf32<0><<<gg, bb, 0, stream>>>(XB2, Wv, Vt, nullptr, temp);
    flash_attn<<<768, 256, 0, stream>>>(Qb, Kb, Vt, Qb, temp);
    gemm_wf32<3><<<gg, bb, 0, stream>>>(Qb, Wo, nullptr, (float*)d_out, temp);
  }
}